// Round 6
// baseline (1167.705 us; speedup 1.0000x reference)
//
#include <hip/hip_runtime.h>
#include <stdint.h>

typedef unsigned short u16;
typedef __attribute__((ext_vector_type(8))) short bf8v;    // 8 bf16 MFMA frag
typedef __attribute__((ext_vector_type(4))) float f32x4;   // C/D frag

#define NB   128
#define NP   512
#define KNN  16
#define CH   64
#define NPB  8                       // points per group
#define GPH  (NB * NP / NPB)         // 8192 groups per phase
#define GRID_MLP 1024                // persistent blocks
#define GPB  (GPH / GRID_MLP)        // 8 groups per block
#define SLOTS 512

// ---------------- workspace layout (bytes) ----------------
#define OFF_IDX   0                  // 4 MB
#define OFF_PART  0x400000           // 1 MB: [L][slot][sum/ssq][ch]
#define PART_BYTES (4 * SLOTS * 2 * 64 * 4)
#define OFF_BN    0x500000           // 2 KB
#define OFF_WN    0x500800           // 8 KB bf16 [o][c]
#define OFF_WC    0x502800
#define OFF_W1B   0x504800
#define OFF_W2B   0x506800
#define OFF_SCWB  0x508800
#define OFF_FB16  0x600000           // 8.4 MB bf16 feats [n*NP+p][64]

__device__ __forceinline__ u16 f2bf(float f) {
    union { float f; unsigned u; } v; v.f = f;
    unsigned r = v.u + 0x7fffu + ((v.u >> 16) & 1u);       // RNE
    return (u16)(r >> 16);
}
struct alignas(16) US8 { u16 v[8]; };
__device__ __forceinline__ US8 pack8(float4 f0, float4 f1) {
    US8 u;
    u.v[0]=f2bf(f0.x); u.v[1]=f2bf(f0.y); u.v[2]=f2bf(f0.z); u.v[3]=f2bf(f0.w);
    u.v[4]=f2bf(f1.x); u.v[5]=f2bf(f1.y); u.v[6]=f2bf(f1.z); u.v[7]=f2bf(f1.w);
    return u;
}

// ---------------- weight prep ----------------
__global__ void prep_weights(const float* __restrict__ W0, const float* __restrict__ W1,
                             const float* __restrict__ W2, const float* __restrict__ scW,
                             u16* Wn, u16* Wc, u16* W1b, u16* W2b, u16* scWb) {
    int i = blockIdx.x * 256 + threadIdx.x;                // i = o*64 + c
    if (i < 4096) {
        int o = i >> 6, c = i & 63;
        float a = W0[o * 128 + c], b = W0[o * 128 + 64 + c];
        Wc[i] = f2bf(a - b);
        Wn[i] = f2bf(b);
        W1b[i]  = f2bf(W1[i]);
        W2b[i]  = f2bf(W2[i]);
        scWb[i] = f2bf(scW[i]);
    }
}

__global__ void feats_to_bf16(const float* __restrict__ feats, u16* __restrict__ fb16) {
    size_t i = ((size_t)blockIdx.x * 256 + threadIdx.x) * 8;
    float4 f0 = *(const float4*)(feats + i);
    float4 f1 = *(const float4*)(feats + i + 4);
    *(US8*)(fb16 + i) = pack8(f0, f1);
}

// ---------------- KNN (verified exact vs reference) ----------------
// (256,2): VGPR cap 256 — key[17] (34 VGPRs) can never spill regardless of
// co-compile context (R3 lesson).
__global__ __launch_bounds__(256, 2)
void knn_kernel(const float* __restrict__ pts, int* __restrict__ idx) {
#pragma clang fp contract(off)
    __shared__ __align__(16) float4 sp[NP];
    const int tid = threadIdx.x;
    const int n = blockIdx.x >> 1;
    const float* pb = pts + (size_t)n * NP * 2;
    for (int i = tid; i < NP; i += 256) {
        float x = pb[i * 2], y = pb[i * 2 + 1];
        float r = x * x + y * y;
        sp[i] = make_float4(x, y, r, 0.f);
    }
    __syncthreads();
    const int p = ((blockIdx.x & 1) << 8) + tid;
    const float xp = sp[p].x, yp = sp[p].y, rp = sp[p].z;

    unsigned long long key[17];
#pragma unroll
    for (int j = 0; j < 17; ++j) key[j] = ~0ull;

    for (int q = 0; q < NP; ++q) {
        float4 sq = sp[q];
        float m = xp * sq.x + yp * sq.y;
        float d = (rp - 2.0f * m) + sq.z;
        unsigned int ub = __float_as_uint(d);
        ub = (ub & 0x80000000u) ? ~ub : (ub | 0x80000000u);
        unsigned long long kk = ((unsigned long long)ub << 32) | (unsigned)q;
        if (kk < key[16]) {
#pragma unroll
            for (int j = 16; j >= 1; --j) {
                unsigned long long prev = key[j - 1], cur = key[j];
                unsigned long long nc = kk < cur ? kk : cur;
                key[j] = (kk < prev) ? prev : nc;
            }
            if (kk < key[0]) key[0] = kk;
        }
    }
    int* ob = idx + ((size_t)n * NP + p) * KNN;
#pragma unroll
    for (int k = 0; k < KNN; ++k)
        ob[k] = (int)(unsigned)(key[k + 1] & 0xffffffffu);
}

// ---------------- BN finalize ----------------
__global__ void finalize_bn(const float* __restrict__ part, float* __restrict__ bn,
                            const float* g0, const float* b0, const float* g1,
                            const float* b1, const float* g2, const float* b2,
                            const float* scg, const float* scb, int mapA, int mapB) {
    int L = (blockIdx.x == 0) ? mapA : mapB;
    int o = threadIdx.x;
    const float* g = (L == 0) ? g0 : (L == 1) ? g1 : (L == 2) ? g2 : scg;
    const float* b = (L == 0) ? b0 : (L == 1) ? b1 : (L == 2) ? b2 : scb;
    float cnt = (L == 3) ? (float)(NB * NP) : (float)(NB * NP * KNN);
    float s = 0.f, ss = 0.f;
    for (int slot = 0; slot < SLOTS; ++slot) {
        s  += part[((L * SLOTS + slot) * 2 + 0) * 64 + o];
        ss += part[((L * SLOTS + slot) * 2 + 1) * 64 + o];
    }
    float mu  = s / cnt;
    float var = fmaxf(ss / cnt - mu * mu, 0.f);
    float sc  = g[o] * rsqrtf(var + 1e-5f);
    bn[L * 128 + o]      = sc;
    bn[L * 128 + 64 + o] = b[o] - mu * sc;
}

#define MFMA16(a, b, c) __builtin_amdgcn_mfma_f32_16x16x32_bf16(a, b, c, 0, 0, 0)

struct SA { f32x4 a0, a1, a2, a3; };   // named fields: never address-taken
struct PF { US8 q0, q1, q2, q3; uint2 cen; };  // prefetched gather (~18 VGPRs)

// ---------------- MFMA MLP phases (persistent + prefetch pipeline) ----------------
// (256,4): VGPR cap 128. R4's body compiled at 56 VGPR under this bound; the
// PF prefetch adds ~18 — no spill risk (R3 spilled only at cap 64). Occupancy
// proven non-critical (R4 44% == R5 11% perf); latency per group is the enemy.
template <int PHASE>
__global__ __launch_bounds__(256, 4)
void mlp_phase(const u16* __restrict__ fb16, const int* __restrict__ idx,
               const u16* __restrict__ Wn, const u16* __restrict__ Wc,
               const u16* __restrict__ W1b, const u16* __restrict__ W2b,
               const u16* __restrict__ scWb, const float* __restrict__ bn,
               float* __restrict__ part, float* __restrict__ out) {
    __shared__ char Ab[128 * 128];        // 128 rows x 64ch bf16, XOR-swizzled, wave-local
    __shared__ char cenB[NPB * 128];      // 8 center rows bf16, wave-local
    __shared__ float aux[2048];           // parity-double-buffered stats / P4 scs

    const int tid = threadIdx.x;
    const int lane = tid & 63;
    const int w = tid >> 6;               // wave 0..3: rows w*32..+31, points 2w,2w+1
    const int l15 = lane & 15;
    const int g4 = lane >> 4;
    const int r0 = w * 32 + l15, r1 = r0 + 16;
    const int sw0 = (r0 & 7) << 4;
    // gather geometry (fixed per thread)
    const int gr_ = w * 32 + (lane >> 1);           // owned row 0..127
    const int gh_ = lane & 1;                       // half (32ch)
    const int gp_ = (gr_ >> 4);                     // point 0..7
    const int gk_ = gr_ & 15;                       // neighbor slot
    const int gsw_ = (gr_ & 7) << 4;
    const int cr_ = 2 * w + ((lane >> 4) & 1);      // center row (lanes dup)

    PF pf;
    auto issue_prefetch = [&](int gb2) {
        int n2 = gb2 >> 6;
        int p02 = (gb2 & 63) * NPB;
        size_t rb2 = (size_t)n2 * NP + p02;
        int src = idx[(rb2 + gp_) * KNN + gk_];
        const US8* gp = (const US8*)(fb16 + ((size_t)n2 * NP + src) * CH + gh_ * 32);
        pf.q0 = gp[0]; pf.q1 = gp[1]; pf.q2 = gp[2]; pf.q3 = gp[3];
        pf.cen = ((const uint2*)(fb16 + (rb2 + cr_) * CH))[lane & 15];
    };

    issue_prefetch(blockIdx.x);           // prologue

    for (int it = 0; it < GPB; ++it) {
        const int gb = blockIdx.x + it * GRID_MLP;
        const int par = it & 1;
        const int pbase = par * 1024;
        const int n = gb >> 6;
        const int p0 = (gb & 63) * NPB;
        const size_t rowbase = (size_t)n * NP + p0;

        // ---- stage prefetched gather -> LDS (wave-local; DS in-order per wave) ----
        {
            char* rb = Ab + gr_ * 128;
            *(US8*)(rb + ((gh_ * 64 +  0) ^ gsw_)) = pf.q0;
            *(US8*)(rb + ((gh_ * 64 + 16) ^ gsw_)) = pf.q1;
            *(US8*)(rb + ((gh_ * 64 + 32) ^ gsw_)) = pf.q2;
            *(US8*)(rb + ((gh_ * 64 + 48) ^ gsw_)) = pf.q3;
            if (lane < 32)
                ((uint2*)(cenB + cr_ * 128))[lane & 15] = pf.cen;
        }
        // ---- issue next group's gather now; consumed next iteration ----
        if (it + 1 < GPB) issue_prefetch(gb + GRID_MLP);

        f32x4 acc[2][4];
#pragma unroll
        for (int rt = 0; rt < 2; ++rt)
#pragma unroll
            for (int ct = 0; ct < 4; ++ct) acc[rt][ct] = (f32x4){0.f, 0.f, 0.f, 0.f};

        auto layerA = [&](const u16* Wb) {
#pragma unroll
            for (int ks = 0; ks < 2; ++ks) {
                bf8v a0 = *(const bf8v*)(Ab + r0 * 128 + ((ks * 64 + g4 * 16) ^ sw0));
                bf8v a1 = *(const bf8v*)(Ab + r1 * 128 + ((ks * 64 + g4 * 16) ^ sw0));
#pragma unroll
                for (int ct = 0; ct < 4; ++ct) {
                    bf8v b = *(const bf8v*)((const char*)Wb + (ct * 16 + l15) * 128 + ks * 64 + g4 * 16);
                    acc[0][ct] = MFMA16(a0, b, acc[0][ct]);
                    acc[1][ct] = MFMA16(a1, b, acc[1][ct]);
                }
            }
        };
        auto layerC = [&](const u16* Wb) {
#pragma unroll
            for (int ks = 0; ks < 2; ++ks) {
                bf8v a0 = *(const bf8v*)(cenB + (2 * w) * 128 + ks * 64 + g4 * 16);
                bf8v a1 = *(const bf8v*)(cenB + (2 * w + 1) * 128 + ks * 64 + g4 * 16);
#pragma unroll
                for (int ct = 0; ct < 4; ++ct) {
                    bf8v b = *(const bf8v*)((const char*)Wb + (ct * 16 + l15) * 128 + ks * 64 + g4 * 16);
                    acc[0][ct] = MFMA16(a0, b, acc[0][ct]);
                    acc[1][ct] = MFMA16(a1, b, acc[1][ct]);
                }
            }
        };
        auto short_mfma = [&]() -> SA {
            SA r;
            r.a0 = (f32x4){0,0,0,0}; r.a1 = (f32x4){0,0,0,0};
            r.a2 = (f32x4){0,0,0,0}; r.a3 = (f32x4){0,0,0,0};
#pragma unroll
            for (int ks = 0; ks < 2; ++ks) {
                int arow = (l15 < 2) ? (2 * w + l15) : (2 * w);
                bf8v a = *(const bf8v*)(cenB + arow * 128 + ks * 64 + g4 * 16);
                bf8v b0 = *(const bf8v*)((const char*)scWb + (0 * 16 + l15) * 128 + ks * 64 + g4 * 16);
                bf8v b1 = *(const bf8v*)((const char*)scWb + (1 * 16 + l15) * 128 + ks * 64 + g4 * 16);
                bf8v b2 = *(const bf8v*)((const char*)scWb + (2 * 16 + l15) * 128 + ks * 64 + g4 * 16);
                bf8v b3 = *(const bf8v*)((const char*)scWb + (3 * 16 + l15) * 128 + ks * 64 + g4 * 16);
                r.a0 = MFMA16(a, b0, r.a0);
                r.a1 = MFMA16(a, b1, r.a1);
                r.a2 = MFMA16(a, b2, r.a2);
                r.a3 = MFMA16(a, b3, r.a3);
            }
            return r;
        };

        auto reduceToAux = [&](int off) {   // -> aux[pbase+off .. +511]
#pragma unroll
            for (int ct = 0; ct < 4; ++ct) {
                float a = 0.f, b = 0.f;
#pragma unroll
                for (int rt = 0; rt < 2; ++rt)
#pragma unroll
                    for (int j = 0; j < 4; ++j) { float v = acc[rt][ct][j]; a += v; b += v * v; }
                a += __shfl_xor(a, 16); a += __shfl_xor(a, 32);
                b += __shfl_xor(b, 16); b += __shfl_xor(b, 32);
                if (lane < 16) {
                    aux[pbase + off + w * 64 + ct * 16 + lane]       = a;
                    aux[pbase + off + 256 + w * 64 + ct * 16 + lane] = b;
                }
            }
        };
        auto flushStats = [&](int L, int off) {  // after barrier; fire-and-forget atomics
            if (tid < 128) {
                int j = tid >> 6, ch = tid & 63;
                int base = pbase + off + j * 256 + ch;
                float t = aux[base] + aux[base + 64] + aux[base + 128] + aux[base + 192];
                atomicAdd(&part[((L * SLOTS + (gb & (SLOTS - 1))) * 2 + j) * 64 + ch], t);
            }
        };

        auto bnwb = [&](int L) {
#pragma unroll
            for (int ct = 0; ct < 4; ++ct) {
                int ch = ct * 16 + l15;
                float sc = bn[L * 128 + ch], sh = bn[L * 128 + 64 + ch];
#pragma unroll
                for (int rt = 0; rt < 2; ++rt)
#pragma unroll
                    for (int j = 0; j < 4; ++j) {
                        int gr = w * 32 + rt * 16 + g4 * 4 + j;
                        float v = fmaxf(fmaf(acc[rt][ct][j], sc, sh), 0.f);
                        *(u16*)(Ab + gr * 128 + ((ch * 2) ^ ((gr & 7) << 4))) = f2bf(v);
                        acc[rt][ct][j] = 0.f;
                    }
            }
        };

        // ---- layer 1: Wn over neighbors + Wc over centers ----
        layerA(Wn);
        layerC(Wc);

        if (PHASE == 1) {
            reduceToAux(0);
            SA a2 = short_mfma();
            // masked shortcut stats (valid: g4==0, j<2) -> off 512
            {
                float s0, s1, s2, s3, q0, q1, q2, q3, u, v;
                u = (g4 == 0) ? a2.a0[0] : 0.f; v = (g4 == 0) ? a2.a0[1] : 0.f;
                s0 = u + v; q0 = u * u + v * v;
                u = (g4 == 0) ? a2.a1[0] : 0.f; v = (g4 == 0) ? a2.a1[1] : 0.f;
                s1 = u + v; q1 = u * u + v * v;
                u = (g4 == 0) ? a2.a2[0] : 0.f; v = (g4 == 0) ? a2.a2[1] : 0.f;
                s2 = u + v; q2 = u * u + v * v;
                u = (g4 == 0) ? a2.a3[0] : 0.f; v = (g4 == 0) ? a2.a3[1] : 0.f;
                s3 = u + v; q3 = u * u + v * v;
                s0 += __shfl_xor(s0, 16); s0 += __shfl_xor(s0, 32);
                s1 += __shfl_xor(s1, 16); s1 += __shfl_xor(s1, 32);
                s2 += __shfl_xor(s2, 16); s2 += __shfl_xor(s2, 32);
                s3 += __shfl_xor(s3, 16); s3 += __shfl_xor(s3, 32);
                q0 += __shfl_xor(q0, 16); q0 += __shfl_xor(q0, 32);
                q1 += __shfl_xor(q1, 16); q1 += __shfl_xor(q1, 32);
                q2 += __shfl_xor(q2, 16); q2 += __shfl_xor(q2, 32);
                q3 += __shfl_xor(q3, 16); q3 += __shfl_xor(q3, 32);
                if (lane < 16) {
                    aux[pbase + 512 + w * 64 +  0 + lane] = s0;
                    aux[pbase + 512 + w * 64 + 16 + lane] = s1;
                    aux[pbase + 512 + w * 64 + 32 + lane] = s2;
                    aux[pbase + 512 + w * 64 + 48 + lane] = s3;
                    aux[pbase + 768 + w * 64 +  0 + lane] = q0;
                    aux[pbase + 768 + w * 64 + 16 + lane] = q1;
                    aux[pbase + 768 + w * 64 + 32 + lane] = q2;
                    aux[pbase + 768 + w * 64 + 48 + lane] = q3;
                }
            }
            __syncthreads();
            flushStats(0, 0);
            flushStats(3, 512);
            continue;                      // parity buffer: no trailing barrier
        }

        bnwb(0);
        layerA(W1b);
        if (PHASE == 2) {
            reduceToAux(0);
            __syncthreads();
            flushStats(1, 0);
            continue;
        }

        bnwb(1);
        layerA(W2b);
        if (PHASE == 3) {
            reduceToAux(0);
            __syncthreads();
            flushStats(2, 0);
            continue;
        }

        // ---- PHASE 4 (barrier-free): mean_k + shortcut + out ----
        {
            float m0[4], m1[4];
#pragma unroll
            for (int ct = 0; ct < 4; ++ct) {
                int ch = ct * 16 + l15;
                float sc = bn[2 * 128 + ch], sh = bn[2 * 128 + 64 + ch];
                float ma = 0.f, mb = 0.f;
#pragma unroll
                for (int j = 0; j < 4; ++j) {
                    ma += fmaxf(fmaf(acc[0][ct][j], sc, sh), 0.f);
                    mb += fmaxf(fmaf(acc[1][ct][j], sc, sh), 0.f);
                }
                ma += __shfl_xor(ma, 16); ma += __shfl_xor(ma, 32);
                mb += __shfl_xor(mb, 16); mb += __shfl_xor(mb, 32);
                m0[ct] = ma; m1[ct] = mb;
            }
            SA a2 = short_mfma();
            float (*scs)[64] = (float(*)[64])aux;  // wave-private rows 2w,2w+1
            if (g4 == 0) {
                int ch0 = l15, ch1 = 16 + l15, ch2 = 32 + l15, ch3 = 48 + l15;
                float sA = bn[384 + ch0], hA = bn[448 + ch0];
                float sB = bn[384 + ch1], hB = bn[448 + ch1];
                float sC = bn[384 + ch2], hC = bn[448 + ch2];
                float sD = bn[384 + ch3], hD = bn[448 + ch3];
                scs[2 * w + 0][ch0] = fmaxf(fmaf(a2.a0[0], sA, hA), 0.f);
                scs[2 * w + 1][ch0] = fmaxf(fmaf(a2.a0[1], sA, hA), 0.f);
                scs[2 * w + 0][ch1] = fmaxf(fmaf(a2.a1[0], sB, hB), 0.f);
                scs[2 * w + 1][ch1] = fmaxf(fmaf(a2.a1[1], sB, hB), 0.f);
                scs[2 * w + 0][ch2] = fmaxf(fmaf(a2.a2[0], sC, hC), 0.f);
                scs[2 * w + 1][ch2] = fmaxf(fmaf(a2.a2[1], sC, hC), 0.f);
                scs[2 * w + 0][ch3] = fmaxf(fmaf(a2.a3[0], sD, hD), 0.f);
                scs[2 * w + 1][ch3] = fmaxf(fmaf(a2.a3[1], sD, hD), 0.f);
            }
            int ph = g4 >> 1;
            int p = 2 * w + ph;
            int cb2 = g4 & 1;
            float mlo0 = cb2 ? m0[2] : m0[0], mhi0 = cb2 ? m1[2] : m1[0];
            float mlo1 = cb2 ? m0[3] : m0[1], mhi1 = cb2 ? m1[3] : m1[1];
            float mva = ph ? mhi0 : mlo0;
            float mvb = ph ? mhi1 : mlo1;
            int ch0 = (cb2 * 2) * 16 + l15;
            int ch1 = ch0 + 16;
            float* ob = out + (rowbase + p) * CH;
            ob[ch0] = mva * 0.0625f + scs[p][ch0];
            ob[ch1] = mvb * 0.0625f + scs[p][ch1];
        }
    }
}

extern "C" void kernel_launch(void* const* d_in, const int* in_sizes, int n_in,
                              void* d_out, int out_size, void* d_ws, size_t ws_size,
                              hipStream_t stream) {
    const float* points = (const float*)d_in[0];
    const float* feats  = (const float*)d_in[1];
    const float* W0  = (const float*)d_in[2];
    const float* g0  = (const float*)d_in[3];
    const float* b0  = (const float*)d_in[4];
    const float* W1  = (const float*)d_in[5];
    const float* g1  = (const float*)d_in[6];
    const float* b1  = (const float*)d_in[7];
    const float* W2  = (const float*)d_in[8];
    const float* g2  = (const float*)d_in[9];
    const float* b2  = (const float*)d_in[10];
    const float* scW = (const float*)d_in[11];
    const float* scg = (const float*)d_in[12];
    const float* scb = (const float*)d_in[13];
    float* out = (float*)d_out;

    char* ws = (char*)d_ws;
    int*   idx  = (int*)(ws + OFF_IDX);
    float* part = (float*)(ws + OFF_PART);
    float* bn   = (float*)(ws + OFF_BN);
    u16*   Wn   = (u16*)(ws + OFF_WN);
    u16*   Wc   = (u16*)(ws + OFF_WC);
    u16*   W1b  = (u16*)(ws + OFF_W1B);
    u16*   W2b  = (u16*)(ws + OFF_W2B);
    u16*   scWb = (u16*)(ws + OFF_SCWB);
    u16*   fb16 = (u16*)(ws + OFF_FB16);

    hipMemsetAsync(part, 0, PART_BYTES, stream);
    prep_weights<<<16, 256, 0, stream>>>(W0, W1, W2, scW, Wn, Wc, W1b, W2b, scWb);
    feats_to_bf16<<<2048, 256, 0, stream>>>(feats, fb16);
    knn_kernel<<<NB * 2, 256, 0, stream>>>(points, idx);

    mlp_phase<1><<<GRID_MLP, 256, 0, stream>>>(fb16, idx, Wn, Wc, W1b, W2b, scWb, bn, part, out);
    finalize_bn<<<2, 64, 0, stream>>>(part, bn, g0, b0, g1, b1, g2, b2, scg, scb, 0, 3);
    mlp_phase<2><<<GRID_MLP, 256, 0, stream>>>(fb16, idx, Wn, Wc, W1b, W2b, scWb, bn, part, out);
    finalize_bn<<<1, 64, 0, stream>>>(part, bn, g0, b0, g1, b1, g2, b2, scg, scb, 1, 1);
    mlp_phase<3><<<GRID_MLP, 256, 0, stream>>>(fb16, idx, Wn, Wc, W1b, W2b, scWb, bn, part, out);
    finalize_bn<<<1, 64, 0, stream>>>(part, bn, g0, b0, g1, b1, g2, b2, scg, scb, 2, 2);
    mlp_phase<4><<<GRID_MLP, 256, 0, stream>>>(fb16, idx, Wn, Wc, W1b, W2b, scWb, bn, part, out);
}

// Round 7
// 675.915 us; speedup vs baseline: 1.7276x; 1.7276x over previous
//
#include <hip/hip_runtime.h>
#include <stdint.h>

typedef unsigned short u16;
typedef __attribute__((ext_vector_type(8))) short bf8v;    // 8 bf16 MFMA frag
typedef __attribute__((ext_vector_type(4))) float f32x4;   // C/D frag

#define NB   128
#define NP   512
#define KNN  16
#define CH   64
#define NPB  8                       // points per group
#define GPH  (NB * NP / NPB)         // 8192 groups per phase
#define GRID_MLP 1024                // persistent blocks
#define GPB  (GPH / GRID_MLP)        // 8 groups per block
#define SLOTS 512

// ---------------- workspace layout (bytes) ----------------
#define OFF_IDX   0                  // 4 MB
#define OFF_PART  0x400000           // 1 MB: [L][slot][sum/ssq][ch]
#define PART_BYTES (4 * SLOTS * 2 * 64 * 4)
#define OFF_BN    0x500000           // 2 KB
#define OFF_WN    0x500800           // 8 KB bf16 [o][c]
#define OFF_WC    0x502800
#define OFF_W1B   0x504800
#define OFF_W2B   0x506800
#define OFF_SCWB  0x508800
#define OFF_FB16  0x600000           // 8.4 MB bf16 feats [n*NP+p][64]

__device__ __forceinline__ u16 f2bf(float f) {
    union { float f; unsigned u; } v; v.f = f;
    unsigned r = v.u + 0x7fffu + ((v.u >> 16) & 1u);       // RNE
    return (u16)(r >> 16);
}
struct alignas(16) US8 { u16 v[8]; };
__device__ __forceinline__ US8 pack8(float4 f0, float4 f1) {
    US8 u;
    u.v[0]=f2bf(f0.x); u.v[1]=f2bf(f0.y); u.v[2]=f2bf(f0.z); u.v[3]=f2bf(f0.w);
    u.v[4]=f2bf(f1.x); u.v[5]=f2bf(f1.y); u.v[6]=f2bf(f1.z); u.v[7]=f2bf(f1.w);
    return u;
}

// ---------------- weight prep ----------------
__global__ void prep_weights(const float* __restrict__ W0, const float* __restrict__ W1,
                             const float* __restrict__ W2, const float* __restrict__ scW,
                             u16* Wn, u16* Wc, u16* W1b, u16* W2b, u16* scWb) {
    int i = blockIdx.x * 256 + threadIdx.x;                // i = o*64 + c
    if (i < 4096) {
        int o = i >> 6, c = i & 63;
        float a = W0[o * 128 + c], b = W0[o * 128 + 64 + c];
        Wc[i] = f2bf(a - b);
        Wn[i] = f2bf(b);
        W1b[i]  = f2bf(W1[i]);
        W2b[i]  = f2bf(W2[i]);
        scWb[i] = f2bf(scW[i]);
    }
}

__global__ void feats_to_bf16(const float* __restrict__ feats, u16* __restrict__ fb16) {
    size_t i = ((size_t)blockIdx.x * 256 + threadIdx.x) * 8;
    float4 f0 = *(const float4*)(feats + i);
    float4 f1 = *(const float4*)(feats + i + 4);
    *(US8*)(fb16 + i) = pack8(f0, f1);
}

// ---------------- KNN (verified exact vs reference) ----------------
// (256,2): VGPR cap 256 — key[17] (34 VGPRs) can never spill regardless of
// co-compile context (R3 lesson).
__global__ __launch_bounds__(256, 2)
void knn_kernel(const float* __restrict__ pts, int* __restrict__ idx) {
#pragma clang fp contract(off)
    __shared__ __align__(16) float4 sp[NP];
    const int tid = threadIdx.x;
    const int n = blockIdx.x >> 1;
    const float* pb = pts + (size_t)n * NP * 2;
    for (int i = tid; i < NP; i += 256) {
        float x = pb[i * 2], y = pb[i * 2 + 1];
        float r = x * x + y * y;
        sp[i] = make_float4(x, y, r, 0.f);
    }
    __syncthreads();
    const int p = ((blockIdx.x & 1) << 8) + tid;
    const float xp = sp[p].x, yp = sp[p].y, rp = sp[p].z;

    unsigned long long key[17];
#pragma unroll
    for (int j = 0; j < 17; ++j) key[j] = ~0ull;

    for (int q = 0; q < NP; ++q) {
        float4 sq = sp[q];
        float m = xp * sq.x + yp * sq.y;
        float d = (rp - 2.0f * m) + sq.z;
        unsigned int ub = __float_as_uint(d);
        ub = (ub & 0x80000000u) ? ~ub : (ub | 0x80000000u);
        unsigned long long kk = ((unsigned long long)ub << 32) | (unsigned)q;
        if (kk < key[16]) {
#pragma unroll
            for (int j = 16; j >= 1; --j) {
                unsigned long long prev = key[j - 1], cur = key[j];
                unsigned long long nc = kk < cur ? kk : cur;
                key[j] = (kk < prev) ? prev : nc;
            }
            if (kk < key[0]) key[0] = kk;
        }
    }
    int* ob = idx + ((size_t)n * NP + p) * KNN;
#pragma unroll
    for (int k = 0; k < KNN; ++k)
        ob[k] = (int)(unsigned)(key[k + 1] & 0xffffffffu);
}

// ---------------- BN finalize ----------------
__global__ void finalize_bn(const float* __restrict__ part, float* __restrict__ bn,
                            const float* g0, const float* b0, const float* g1,
                            const float* b1, const float* g2, const float* b2,
                            const float* scg, const float* scb, int mapA, int mapB) {
    int L = (blockIdx.x == 0) ? mapA : mapB;
    int o = threadIdx.x;
    const float* g = (L == 0) ? g0 : (L == 1) ? g1 : (L == 2) ? g2 : scg;
    const float* b = (L == 0) ? b0 : (L == 1) ? b1 : (L == 2) ? b2 : scb;
    float cnt = (L == 3) ? (float)(NB * NP) : (float)(NB * NP * KNN);
    float s = 0.f, ss = 0.f;
    for (int slot = 0; slot < SLOTS; ++slot) {
        s  += part[((L * SLOTS + slot) * 2 + 0) * 64 + o];
        ss += part[((L * SLOTS + slot) * 2 + 1) * 64 + o];
    }
    float mu  = s / cnt;
    float var = fmaxf(ss / cnt - mu * mu, 0.f);
    float sc  = g[o] * rsqrtf(var + 1e-5f);
    bn[L * 128 + o]      = sc;
    bn[L * 128 + 64 + o] = b[o] - mu * sc;
}

#define MFMA16(a, b, c) __builtin_amdgcn_mfma_f32_16x16x32_bf16(a, b, c, 0, 0, 0)

struct SA { f32x4 a0, a1, a2, a3; };   // named fields: never address-taken

// ---------------- MFMA MLP phases (persistent + prefetch pipeline) ----------------
// PLAIN __launch_bounds__(256): the only proven spill-free config for this
// body (R5: 160 VGPR, clean). R6's (256,4) made the backend allocate 64 VGPR
// and spill the prefetch state to scratch (FETCH 916 MB/phase). Prefetch kept
// in NAMED scalars, loaded inline — no struct, no captured-by-ref lambda.
template <int PHASE>
__global__ __launch_bounds__(256)
void mlp_phase(const u16* __restrict__ fb16, const int* __restrict__ idx,
               const u16* __restrict__ Wn, const u16* __restrict__ Wc,
               const u16* __restrict__ W1b, const u16* __restrict__ W2b,
               const u16* __restrict__ scWb, const float* __restrict__ bn,
               float* __restrict__ part, float* __restrict__ out) {
    __shared__ char Ab[128 * 128];        // 128 rows x 64ch bf16, XOR-swizzled, wave-local
    __shared__ char cenB[NPB * 128];      // 8 center rows bf16, wave-local
    __shared__ float aux[2048];           // parity-double-buffered stats / P4 scs

    const int tid = threadIdx.x;
    const int lane = tid & 63;
    const int w = tid >> 6;               // wave 0..3: rows w*32..+31, points 2w,2w+1
    const int l15 = lane & 15;
    const int g4 = lane >> 4;
    const int r0 = w * 32 + l15, r1 = r0 + 16;
    const int sw0 = (r0 & 7) << 4;
    // gather geometry (fixed per thread)
    const int gr_ = w * 32 + (lane >> 1);           // owned row 0..127
    const int gh_ = lane & 1;                       // half (32ch)
    const int gp_ = (gr_ >> 4);                     // point 0..7
    const int gk_ = gr_ & 15;                       // neighbor slot
    const int gsw_ = (gr_ & 7) << 4;
    const int cr_ = 2 * w + ((lane >> 4) & 1);      // center row (lanes dup)

    // ---- prologue prefetch (named scalars; manually inlined) ----
    US8 pf_q0, pf_q1, pf_q2, pf_q3; uint2 pf_cen;
    {
        const int gb2 = blockIdx.x;
        const int n2 = gb2 >> 6;
        const size_t rb2 = (size_t)n2 * NP + (gb2 & 63) * NPB;
        int src = idx[(rb2 + gp_) * KNN + gk_];
        const US8* gp = (const US8*)(fb16 + ((size_t)n2 * NP + src) * CH + gh_ * 32);
        pf_q0 = gp[0]; pf_q1 = gp[1]; pf_q2 = gp[2]; pf_q3 = gp[3];
        pf_cen = ((const uint2*)(fb16 + (rb2 + cr_) * CH))[lane & 15];
    }

    for (int it = 0; it < GPB; ++it) {
        const int gb = blockIdx.x + it * GRID_MLP;
        const int pbase = (it & 1) * 1024;
        const int n = gb >> 6;
        const int p0 = (gb & 63) * NPB;
        const size_t rowbase = (size_t)n * NP + p0;

        // ---- stage prefetched gather -> LDS (wave-local; DS in-order per wave) ----
        {
            char* rb = Ab + gr_ * 128;
            *(US8*)(rb + ((gh_ * 64 +  0) ^ gsw_)) = pf_q0;
            *(US8*)(rb + ((gh_ * 64 + 16) ^ gsw_)) = pf_q1;
            *(US8*)(rb + ((gh_ * 64 + 32) ^ gsw_)) = pf_q2;
            *(US8*)(rb + ((gh_ * 64 + 48) ^ gsw_)) = pf_q3;
            if (lane < 32)
                ((uint2*)(cenB + cr_ * 128))[lane & 15] = pf_cen;
        }
        // ---- issue next group's gather now; consumed next iteration ----
        if (it + 1 < GPB) {
            const int gb2 = gb + GRID_MLP;
            const int n2 = gb2 >> 6;
            const size_t rb2 = (size_t)n2 * NP + (gb2 & 63) * NPB;
            int src = idx[(rb2 + gp_) * KNN + gk_];
            const US8* gp = (const US8*)(fb16 + ((size_t)n2 * NP + src) * CH + gh_ * 32);
            pf_q0 = gp[0]; pf_q1 = gp[1]; pf_q2 = gp[2]; pf_q3 = gp[3];
            pf_cen = ((const uint2*)(fb16 + (rb2 + cr_) * CH))[lane & 15];
        }

        f32x4 acc[2][4];
#pragma unroll
        for (int rt = 0; rt < 2; ++rt)
#pragma unroll
            for (int ct = 0; ct < 4; ++ct) acc[rt][ct] = (f32x4){0.f, 0.f, 0.f, 0.f};

        auto layerA = [&](const u16* Wb) {
#pragma unroll
            for (int ks = 0; ks < 2; ++ks) {
                bf8v a0 = *(const bf8v*)(Ab + r0 * 128 + ((ks * 64 + g4 * 16) ^ sw0));
                bf8v a1 = *(const bf8v*)(Ab + r1 * 128 + ((ks * 64 + g4 * 16) ^ sw0));
#pragma unroll
                for (int ct = 0; ct < 4; ++ct) {
                    bf8v b = *(const bf8v*)((const char*)Wb + (ct * 16 + l15) * 128 + ks * 64 + g4 * 16);
                    acc[0][ct] = MFMA16(a0, b, acc[0][ct]);
                    acc[1][ct] = MFMA16(a1, b, acc[1][ct]);
                }
            }
        };
        auto layerC = [&](const u16* Wb) {
#pragma unroll
            for (int ks = 0; ks < 2; ++ks) {
                bf8v a0 = *(const bf8v*)(cenB + (2 * w) * 128 + ks * 64 + g4 * 16);
                bf8v a1 = *(const bf8v*)(cenB + (2 * w + 1) * 128 + ks * 64 + g4 * 16);
#pragma unroll
                for (int ct = 0; ct < 4; ++ct) {
                    bf8v b = *(const bf8v*)((const char*)Wb + (ct * 16 + l15) * 128 + ks * 64 + g4 * 16);
                    acc[0][ct] = MFMA16(a0, b, acc[0][ct]);
                    acc[1][ct] = MFMA16(a1, b, acc[1][ct]);
                }
            }
        };
        auto short_mfma = [&]() -> SA {
            SA r;
            r.a0 = (f32x4){0,0,0,0}; r.a1 = (f32x4){0,0,0,0};
            r.a2 = (f32x4){0,0,0,0}; r.a3 = (f32x4){0,0,0,0};
#pragma unroll
            for (int ks = 0; ks < 2; ++ks) {
                int arow = (l15 < 2) ? (2 * w + l15) : (2 * w);
                bf8v a = *(const bf8v*)(cenB + arow * 128 + ks * 64 + g4 * 16);
                bf8v b0 = *(const bf8v*)((const char*)scWb + (0 * 16 + l15) * 128 + ks * 64 + g4 * 16);
                bf8v b1 = *(const bf8v*)((const char*)scWb + (1 * 16 + l15) * 128 + ks * 64 + g4 * 16);
                bf8v b2 = *(const bf8v*)((const char*)scWb + (2 * 16 + l15) * 128 + ks * 64 + g4 * 16);
                bf8v b3 = *(const bf8v*)((const char*)scWb + (3 * 16 + l15) * 128 + ks * 64 + g4 * 16);
                r.a0 = MFMA16(a, b0, r.a0);
                r.a1 = MFMA16(a, b1, r.a1);
                r.a2 = MFMA16(a, b2, r.a2);
                r.a3 = MFMA16(a, b3, r.a3);
            }
            return r;
        };

        auto reduceToAux = [&](int off) {   // -> aux[pbase+off .. +511]
#pragma unroll
            for (int ct = 0; ct < 4; ++ct) {
                float a = 0.f, b = 0.f;
#pragma unroll
                for (int rt = 0; rt < 2; ++rt)
#pragma unroll
                    for (int j = 0; j < 4; ++j) { float v = acc[rt][ct][j]; a += v; b += v * v; }
                a += __shfl_xor(a, 16); a += __shfl_xor(a, 32);
                b += __shfl_xor(b, 16); b += __shfl_xor(b, 32);
                if (lane < 16) {
                    aux[pbase + off + w * 64 + ct * 16 + lane]       = a;
                    aux[pbase + off + 256 + w * 64 + ct * 16 + lane] = b;
                }
            }
        };
        auto flushStats = [&](int L, int off) {  // after barrier; fire-and-forget atomics
            if (tid < 128) {
                int j = tid >> 6, ch = tid & 63;
                int base = pbase + off + j * 256 + ch;
                float t = aux[base] + aux[base + 64] + aux[base + 128] + aux[base + 192];
                atomicAdd(&part[((L * SLOTS + (gb & (SLOTS - 1))) * 2 + j) * 64 + ch], t);
            }
        };

        auto bnwb = [&](int L) {
#pragma unroll
            for (int ct = 0; ct < 4; ++ct) {
                int ch = ct * 16 + l15;
                float sc = bn[L * 128 + ch], sh = bn[L * 128 + 64 + ch];
#pragma unroll
                for (int rt = 0; rt < 2; ++rt)
#pragma unroll
                    for (int j = 0; j < 4; ++j) {
                        int gr = w * 32 + rt * 16 + g4 * 4 + j;
                        float v = fmaxf(fmaf(acc[rt][ct][j], sc, sh), 0.f);
                        *(u16*)(Ab + gr * 128 + ((ch * 2) ^ ((gr & 7) << 4))) = f2bf(v);
                        acc[rt][ct][j] = 0.f;
                    }
            }
        };

        // ---- layer 1: Wn over neighbors + Wc over centers ----
        layerA(Wn);
        layerC(Wc);

        if (PHASE == 1) {
            reduceToAux(0);
            SA a2 = short_mfma();
            // masked shortcut stats (valid: g4==0, j<2) -> off 512
            {
                float s0, s1, s2, s3, q0, q1, q2, q3, u, v;
                u = (g4 == 0) ? a2.a0[0] : 0.f; v = (g4 == 0) ? a2.a0[1] : 0.f;
                s0 = u + v; q0 = u * u + v * v;
                u = (g4 == 0) ? a2.a1[0] : 0.f; v = (g4 == 0) ? a2.a1[1] : 0.f;
                s1 = u + v; q1 = u * u + v * v;
                u = (g4 == 0) ? a2.a2[0] : 0.f; v = (g4 == 0) ? a2.a2[1] : 0.f;
                s2 = u + v; q2 = u * u + v * v;
                u = (g4 == 0) ? a2.a3[0] : 0.f; v = (g4 == 0) ? a2.a3[1] : 0.f;
                s3 = u + v; q3 = u * u + v * v;
                s0 += __shfl_xor(s0, 16); s0 += __shfl_xor(s0, 32);
                s1 += __shfl_xor(s1, 16); s1 += __shfl_xor(s1, 32);
                s2 += __shfl_xor(s2, 16); s2 += __shfl_xor(s2, 32);
                s3 += __shfl_xor(s3, 16); s3 += __shfl_xor(s3, 32);
                q0 += __shfl_xor(q0, 16); q0 += __shfl_xor(q0, 32);
                q1 += __shfl_xor(q1, 16); q1 += __shfl_xor(q1, 32);
                q2 += __shfl_xor(q2, 16); q2 += __shfl_xor(q2, 32);
                q3 += __shfl_xor(q3, 16); q3 += __shfl_xor(q3, 32);
                if (lane < 16) {
                    aux[pbase + 512 + w * 64 +  0 + lane] = s0;
                    aux[pbase + 512 + w * 64 + 16 + lane] = s1;
                    aux[pbase + 512 + w * 64 + 32 + lane] = s2;
                    aux[pbase + 512 + w * 64 + 48 + lane] = s3;
                    aux[pbase + 768 + w * 64 +  0 + lane] = q0;
                    aux[pbase + 768 + w * 64 + 16 + lane] = q1;
                    aux[pbase + 768 + w * 64 + 32 + lane] = q2;
                    aux[pbase + 768 + w * 64 + 48 + lane] = q3;
                }
            }
            __syncthreads();
            flushStats(0, 0);
            flushStats(3, 512);
            continue;                      // parity buffer: no trailing barrier
        }

        bnwb(0);
        layerA(W1b);
        if (PHASE == 2) {
            reduceToAux(0);
            __syncthreads();
            flushStats(1, 0);
            continue;
        }

        bnwb(1);
        layerA(W2b);
        if (PHASE == 3) {
            reduceToAux(0);
            __syncthreads();
            flushStats(2, 0);
            continue;
        }

        // ---- PHASE 4 (barrier-free): mean_k + shortcut + out ----
        {
            float m0[4], m1[4];
#pragma unroll
            for (int ct = 0; ct < 4; ++ct) {
                int ch = ct * 16 + l15;
                float sc = bn[2 * 128 + ch], sh = bn[2 * 128 + 64 + ch];
                float ma = 0.f, mb = 0.f;
#pragma unroll
                for (int j = 0; j < 4; ++j) {
                    ma += fmaxf(fmaf(acc[0][ct][j], sc, sh), 0.f);
                    mb += fmaxf(fmaf(acc[1][ct][j], sc, sh), 0.f);
                }
                ma += __shfl_xor(ma, 16); ma += __shfl_xor(ma, 32);
                mb += __shfl_xor(mb, 16); mb += __shfl_xor(mb, 32);
                m0[ct] = ma; m1[ct] = mb;
            }
            SA a2 = short_mfma();
            float (*scs)[64] = (float(*)[64])aux;  // wave-private rows 2w,2w+1
            if (g4 == 0) {
                int ch0 = l15, ch1 = 16 + l15, ch2 = 32 + l15, ch3 = 48 + l15;
                float sA = bn[384 + ch0], hA = bn[448 + ch0];
                float sB = bn[384 + ch1], hB = bn[448 + ch1];
                float sC = bn[384 + ch2], hC = bn[448 + ch2];
                float sD = bn[384 + ch3], hD = bn[448 + ch3];
                scs[2 * w + 0][ch0] = fmaxf(fmaf(a2.a0[0], sA, hA), 0.f);
                scs[2 * w + 1][ch0] = fmaxf(fmaf(a2.a0[1], sA, hA), 0.f);
                scs[2 * w + 0][ch1] = fmaxf(fmaf(a2.a1[0], sB, hB), 0.f);
                scs[2 * w + 1][ch1] = fmaxf(fmaf(a2.a1[1], sB, hB), 0.f);
                scs[2 * w + 0][ch2] = fmaxf(fmaf(a2.a2[0], sC, hC), 0.f);
                scs[2 * w + 1][ch2] = fmaxf(fmaf(a2.a2[1], sC, hC), 0.f);
                scs[2 * w + 0][ch3] = fmaxf(fmaf(a2.a3[0], sD, hD), 0.f);
                scs[2 * w + 1][ch3] = fmaxf(fmaf(a2.a3[1], sD, hD), 0.f);
            }
            int ph = g4 >> 1;
            int p = 2 * w + ph;
            int cb2 = g4 & 1;
            float mlo0 = cb2 ? m0[2] : m0[0], mhi0 = cb2 ? m1[2] : m1[0];
            float mlo1 = cb2 ? m0[3] : m0[1], mhi1 = cb2 ? m1[3] : m1[1];
            float mva = ph ? mhi0 : mlo0;
            float mvb = ph ? mhi1 : mlo1;
            int ch0 = (cb2 * 2) * 16 + l15;
            int ch1 = ch0 + 16;
            float* ob = out + (rowbase + p) * CH;
            ob[ch0] = mva * 0.0625f + scs[p][ch0];
            ob[ch1] = mvb * 0.0625f + scs[p][ch1];
        }
    }
}

extern "C" void kernel_launch(void* const* d_in, const int* in_sizes, int n_in,
                              void* d_out, int out_size, void* d_ws, size_t ws_size,
                              hipStream_t stream) {
    const float* points = (const float*)d_in[0];
    const float* feats  = (const float*)d_in[1];
    const float* W0  = (const float*)d_in[2];
    const float* g0  = (const float*)d_in[3];
    const float* b0  = (const float*)d_in[4];
    const float* W1  = (const float*)d_in[5];
    const float* g1  = (const float*)d_in[6];
    const float* b1  = (const float*)d_in[7];
    const float* W2  = (const float*)d_in[8];
    const float* g2  = (const float*)d_in[9];
    const float* b2  = (const float*)d_in[10];
    const float* scW = (const float*)d_in[11];
    const float* scg = (const float*)d_in[12];
    const float* scb = (const float*)d_in[13];
    float* out = (float*)d_out;

    char* ws = (char*)d_ws;
    int*   idx  = (int*)(ws + OFF_IDX);
    float* part = (float*)(ws + OFF_PART);
    float* bn   = (float*)(ws + OFF_BN);
    u16*   Wn   = (u16*)(ws + OFF_WN);
    u16*   Wc   = (u16*)(ws + OFF_WC);
    u16*   W1b  = (u16*)(ws + OFF_W1B);
    u16*   W2b  = (u16*)(ws + OFF_W2B);
    u16*   scWb = (u16*)(ws + OFF_SCWB);
    u16*   fb16 = (u16*)(ws + OFF_FB16);

    hipMemsetAsync(part, 0, PART_BYTES, stream);
    prep_weights<<<16, 256, 0, stream>>>(W0, W1, W2, scW, Wn, Wc, W1b, W2b, scWb);
    feats_to_bf16<<<2048, 256, 0, stream>>>(feats, fb16);
    knn_kernel<<<NB * 2, 256, 0, stream>>>(points, idx);

    mlp_phase<1><<<GRID_MLP, 256, 0, stream>>>(fb16, idx, Wn, Wc, W1b, W2b, scWb, bn, part, out);
    finalize_bn<<<2, 64, 0, stream>>>(part, bn, g0, b0, g1, b1, g2, b2, scg, scb, 0, 3);
    mlp_phase<2><<<GRID_MLP, 256, 0, stream>>>(fb16, idx, Wn, Wc, W1b, W2b, scWb, bn, part, out);
    finalize_bn<<<1, 64, 0, stream>>>(part, bn, g0, b0, g1, b1, g2, b2, scg, scb, 1, 1);
    mlp_phase<3><<<GRID_MLP, 256, 0, stream>>>(fb16, idx, Wn, Wc, W1b, W2b, scWb, bn, part, out);
    finalize_bn<<<1, 64, 0, stream>>>(part, bn, g0, b0, g1, b1, g2, b2, scg, scb, 2, 2);
    mlp_phase<4><<<GRID_MLP, 256, 0, stream>>>(fb16, idx, Wn, Wc, W1b, W2b, scWb, bn, part, out);
}

// Round 8
// 566.471 us; speedup vs baseline: 2.0614x; 1.1932x over previous
//
#include <hip/hip_runtime.h>
#include <stdint.h>

typedef unsigned short u16;
typedef __attribute__((ext_vector_type(8))) short bf8v;    // 8 bf16 MFMA frag
typedef __attribute__((ext_vector_type(4))) float f32x4;   // C/D frag

#define NB   128
#define NP   512
#define KNN  16
#define CH   64
#define NPB  8                       // points per group
#define GPH  (NB * NP / NPB)         // 8192 groups per phase
#define GRID_MLP 1024                // persistent blocks
#define GPB  8                       // groups per block (2 in flight per iter)
#define SLOTS 512

// ---------------- workspace layout (bytes) ----------------
#define OFF_IDX   0                  // 4 MB
#define OFF_PART  0x400000           // 1 MB: [L][slot][sum/ssq][ch]
#define PART_BYTES (4 * SLOTS * 2 * 64 * 4)
#define OFF_BN    0x500000           // 2 KB
#define OFF_WN    0x500800           // 8 KB bf16 [o][c]
#define OFF_WC    0x502800
#define OFF_W1B   0x504800
#define OFF_W2B   0x506800
#define OFF_SCWB  0x508800
#define OFF_FB16  0x600000           // 8.4 MB bf16 feats [n*NP+p][64]

__device__ __forceinline__ u16 f2bf(float f) {
    union { float f; unsigned u; } v; v.f = f;
    unsigned r = v.u + 0x7fffu + ((v.u >> 16) & 1u);       // RNE
    return (u16)(r >> 16);
}
struct alignas(16) US8 { u16 v[8]; };
__device__ __forceinline__ US8 pack8(float4 f0, float4 f1) {
    US8 u;
    u.v[0]=f2bf(f0.x); u.v[1]=f2bf(f0.y); u.v[2]=f2bf(f0.z); u.v[3]=f2bf(f0.w);
    u.v[4]=f2bf(f1.x); u.v[5]=f2bf(f1.y); u.v[6]=f2bf(f1.z); u.v[7]=f2bf(f1.w);
    return u;
}

// ---------------- weight prep ----------------
__global__ void prep_weights(const float* __restrict__ W0, const float* __restrict__ W1,
                             const float* __restrict__ W2, const float* __restrict__ scW,
                             u16* Wn, u16* Wc, u16* W1b, u16* W2b, u16* scWb) {
    int i = blockIdx.x * 256 + threadIdx.x;                // i = o*64 + c
    if (i < 4096) {
        int o = i >> 6, c = i & 63;
        float a = W0[o * 128 + c], b = W0[o * 128 + 64 + c];
        Wc[i] = f2bf(a - b);
        Wn[i] = f2bf(b);
        W1b[i]  = f2bf(W1[i]);
        W2b[i]  = f2bf(W2[i]);
        scWb[i] = f2bf(scW[i]);
    }
}

__global__ void feats_to_bf16(const float* __restrict__ feats, u16* __restrict__ fb16) {
    size_t i = ((size_t)blockIdx.x * 256 + threadIdx.x) * 8;
    float4 f0 = *(const float4*)(feats + i);
    float4 f1 = *(const float4*)(feats + i + 4);
    *(US8*)(fb16 + i) = pack8(f0, f1);
}

// ---------------- KNN (verified exact vs reference) ----------------
// (256,2): VGPR cap 256 — key[17] (34 VGPRs) can never spill regardless of
// co-compile context (R3 lesson).
__global__ __launch_bounds__(256, 2)
void knn_kernel(const float* __restrict__ pts, int* __restrict__ idx) {
#pragma clang fp contract(off)
    __shared__ __align__(16) float4 sp[NP];
    const int tid = threadIdx.x;
    const int n = blockIdx.x >> 1;
    const float* pb = pts + (size_t)n * NP * 2;
    for (int i = tid; i < NP; i += 256) {
        float x = pb[i * 2], y = pb[i * 2 + 1];
        float r = x * x + y * y;
        sp[i] = make_float4(x, y, r, 0.f);
    }
    __syncthreads();
    const int p = ((blockIdx.x & 1) << 8) + tid;
    const float xp = sp[p].x, yp = sp[p].y, rp = sp[p].z;

    unsigned long long key[17];
#pragma unroll
    for (int j = 0; j < 17; ++j) key[j] = ~0ull;

    for (int q = 0; q < NP; ++q) {
        float4 sq = sp[q];
        float m = xp * sq.x + yp * sq.y;
        float d = (rp - 2.0f * m) + sq.z;
        unsigned int ub = __float_as_uint(d);
        ub = (ub & 0x80000000u) ? ~ub : (ub | 0x80000000u);
        unsigned long long kk = ((unsigned long long)ub << 32) | (unsigned)q;
        if (kk < key[16]) {
#pragma unroll
            for (int j = 16; j >= 1; --j) {
                unsigned long long prev = key[j - 1], cur = key[j];
                unsigned long long nc = kk < cur ? kk : cur;
                key[j] = (kk < prev) ? prev : nc;
            }
            if (kk < key[0]) key[0] = kk;
        }
    }
    int* ob = idx + ((size_t)n * NP + p) * KNN;
#pragma unroll
    for (int k = 0; k < KNN; ++k)
        ob[k] = (int)(unsigned)(key[k + 1] & 0xffffffffu);
}

// ---------------- BN finalize ----------------
__global__ void finalize_bn(const float* __restrict__ part, float* __restrict__ bn,
                            const float* g0, const float* b0, const float* g1,
                            const float* b1, const float* g2, const float* b2,
                            const float* scg, const float* scb, int mapA, int mapB) {
    int L = (blockIdx.x == 0) ? mapA : mapB;
    int o = threadIdx.x;
    const float* g = (L == 0) ? g0 : (L == 1) ? g1 : (L == 2) ? g2 : scg;
    const float* b = (L == 0) ? b0 : (L == 1) ? b1 : (L == 2) ? b2 : scb;
    float cnt = (L == 3) ? (float)(NB * NP) : (float)(NB * NP * KNN);
    float s = 0.f, ss = 0.f;
    for (int slot = 0; slot < SLOTS; ++slot) {
        s  += part[((L * SLOTS + slot) * 2 + 0) * 64 + o];
        ss += part[((L * SLOTS + slot) * 2 + 1) * 64 + o];
    }
    float mu  = s / cnt;
    float var = fmaxf(ss / cnt - mu * mu, 0.f);
    float sc  = g[o] * rsqrtf(var + 1e-5f);
    bn[L * 128 + o]      = sc;
    bn[L * 128 + 64 + o] = b[o] - mu * sc;
}

#define MFMA16(a, b, c) __builtin_amdgcn_mfma_f32_16x16x32_bf16(a, b, c, 0, 0, 0)

// ---------------- MFMA MLP phases: 2 groups in flight per wave ----------------
// Rationale (R7 post-mortem): phases are latency-bound at ~1 wave/SIMD; every
// fix that didn't add co-issuable work (prefetch, occupancy changes, barrier
// diet) was null. Two interleaved group pipelines double the ILP on EVERY
// latency source and share the weight loads. No barriers anywhere: stats are
// reduced in-wave and atomically added per wave (slot includes wave id).
// PLAIN __launch_bounds__(256): only proven spill-free config (R5/R7).
template <int PHASE>
__global__ __launch_bounds__(256)
void mlp_phase(const u16* __restrict__ fb16, const int* __restrict__ idx,
               const u16* __restrict__ Wn, const u16* __restrict__ Wc,
               const u16* __restrict__ W1b, const u16* __restrict__ W2b,
               const u16* __restrict__ scWb, const float* __restrict__ bn,
               float* __restrict__ part, float* __restrict__ out) {
    __shared__ char AbA[128 * 128];       // group A: 128 rows x 64ch bf16, swizzled
    __shared__ char AbB[128 * 128];       // group B
    __shared__ char ceA[NPB * 128];       // center rows
    __shared__ char ceB[NPB * 128];
    __shared__ float scsA[NPB][64];       // P4 shortcut values (wave-private rows)
    __shared__ float scsB[NPB][64];

    const int tid = threadIdx.x;
    const int lane = tid & 63;
    const int w = tid >> 6;               // wave 0..3: rows w*32..+31, points 2w,2w+1
    const int l15 = lane & 15;
    const int g4 = lane >> 4;
    const int r0 = w * 32 + l15, r1 = r0 + 16;
    const int sw0 = (r0 & 7) << 4;
    // gather geometry (fixed per thread)
    const int gr_ = w * 32 + (lane >> 1);
    const int gh_ = lane & 1;
    const int gp_ = gr_ >> 4;
    const int gk_ = gr_ & 15;
    const int gsw_ = (gr_ & 7) << 4;
    const int cr_ = 2 * w + ((lane >> 4) & 1);

    for (int it = 0; it < GPB / 2; ++it) {
        const int gbA = blockIdx.x + it * (2 * GRID_MLP);
        const int gbB = gbA + GRID_MLP;
        const int nA = gbA >> 6, nB = gbB >> 6;
        const size_t rbA = (size_t)nA * NP + (gbA & 63) * NPB;
        const size_t rbB = (size_t)nB * NP + (gbB & 63) * NPB;

        // ---- both gathers issued together (independent chains) ----
        int srcA = idx[(rbA + gp_) * KNN + gk_];
        int srcB = idx[(rbB + gp_) * KNN + gk_];
        const US8* gA = (const US8*)(fb16 + ((size_t)nA * NP + srcA) * CH + gh_ * 32);
        const US8* gB = (const US8*)(fb16 + ((size_t)nB * NP + srcB) * CH + gh_ * 32);
        US8 aq0 = gA[0], aq1 = gA[1], aq2 = gA[2], aq3 = gA[3];
        US8 bq0 = gB[0], bq1 = gB[1], bq2 = gB[2], bq3 = gB[3];
        uint2 acen = ((const uint2*)(fb16 + (rbA + cr_) * CH))[lane & 15];
        uint2 bcen = ((const uint2*)(fb16 + (rbB + cr_) * CH))[lane & 15];
        {
            char* ra = AbA + gr_ * 128;
            *(US8*)(ra + ((gh_ * 64 +  0) ^ gsw_)) = aq0;
            *(US8*)(ra + ((gh_ * 64 + 16) ^ gsw_)) = aq1;
            *(US8*)(ra + ((gh_ * 64 + 32) ^ gsw_)) = aq2;
            *(US8*)(ra + ((gh_ * 64 + 48) ^ gsw_)) = aq3;
            char* rb = AbB + gr_ * 128;
            *(US8*)(rb + ((gh_ * 64 +  0) ^ gsw_)) = bq0;
            *(US8*)(rb + ((gh_ * 64 + 16) ^ gsw_)) = bq1;
            *(US8*)(rb + ((gh_ * 64 + 32) ^ gsw_)) = bq2;
            *(US8*)(rb + ((gh_ * 64 + 48) ^ gsw_)) = bq3;
            if (lane < 32) {
                ((uint2*)(ceA + cr_ * 128))[lane & 15] = acen;
                ((uint2*)(ceB + cr_ * 128))[lane & 15] = bcen;
            }
        }
        // no barrier: all LDS rows produced and consumed by the same wave

        f32x4 accA[2][4], accB[2][4];
#pragma unroll
        for (int rt = 0; rt < 2; ++rt)
#pragma unroll
            for (int ct = 0; ct < 4; ++ct) {
                accA[rt][ct] = (f32x4){0.f, 0.f, 0.f, 0.f};
                accB[rt][ct] = (f32x4){0.f, 0.f, 0.f, 0.f};
            }

        // neighbor layer for both groups; weight loads shared
        auto layer2 = [&](const u16* Wb) {
#pragma unroll
            for (int ks = 0; ks < 2; ++ks) {
                bf8v aA0 = *(const bf8v*)(AbA + r0 * 128 + ((ks * 64 + g4 * 16) ^ sw0));
                bf8v aA1 = *(const bf8v*)(AbA + r1 * 128 + ((ks * 64 + g4 * 16) ^ sw0));
                bf8v aB0 = *(const bf8v*)(AbB + r0 * 128 + ((ks * 64 + g4 * 16) ^ sw0));
                bf8v aB1 = *(const bf8v*)(AbB + r1 * 128 + ((ks * 64 + g4 * 16) ^ sw0));
#pragma unroll
                for (int ct = 0; ct < 4; ++ct) {
                    bf8v b = *(const bf8v*)((const char*)Wb + (ct * 16 + l15) * 128 + ks * 64 + g4 * 16);
                    accA[0][ct] = MFMA16(aA0, b, accA[0][ct]);
                    accA[1][ct] = MFMA16(aA1, b, accA[1][ct]);
                    accB[0][ct] = MFMA16(aB0, b, accB[0][ct]);
                    accB[1][ct] = MFMA16(aB1, b, accB[1][ct]);
                }
            }
        };
        // center layer for both groups
        auto layerC2 = [&](const u16* Wb) {
#pragma unroll
            for (int ks = 0; ks < 2; ++ks) {
                bf8v cA0 = *(const bf8v*)(ceA + (2 * w) * 128 + ks * 64 + g4 * 16);
                bf8v cA1 = *(const bf8v*)(ceA + (2 * w + 1) * 128 + ks * 64 + g4 * 16);
                bf8v cB0 = *(const bf8v*)(ceB + (2 * w) * 128 + ks * 64 + g4 * 16);
                bf8v cB1 = *(const bf8v*)(ceB + (2 * w + 1) * 128 + ks * 64 + g4 * 16);
#pragma unroll
                for (int ct = 0; ct < 4; ++ct) {
                    bf8v b = *(const bf8v*)((const char*)Wb + (ct * 16 + l15) * 128 + ks * 64 + g4 * 16);
                    accA[0][ct] = MFMA16(cA0, b, accA[0][ct]);
                    accA[1][ct] = MFMA16(cA1, b, accA[1][ct]);
                    accB[0][ct] = MFMA16(cB0, b, accB[0][ct]);
                    accB[1][ct] = MFMA16(cB1, b, accB[1][ct]);
                }
            }
        };
        // in-wave stats -> direct atomics, slot keyed by (group, wave): no barrier
        auto stats2 = [&](int L) {
#pragma unroll
            for (int ct = 0; ct < 4; ++ct) {
                float a = 0.f, b = 0.f, c = 0.f, d = 0.f;
#pragma unroll
                for (int rt = 0; rt < 2; ++rt)
#pragma unroll
                    for (int j = 0; j < 4; ++j) {
                        float vA = accA[rt][ct][j]; a += vA; b += vA * vA;
                        float vB = accB[rt][ct][j]; c += vB; d += vB * vB;
                    }
                a += __shfl_xor(a, 16); a += __shfl_xor(a, 32);
                b += __shfl_xor(b, 16); b += __shfl_xor(b, 32);
                c += __shfl_xor(c, 16); c += __shfl_xor(c, 32);
                d += __shfl_xor(d, 16); d += __shfl_xor(d, 32);
                if (lane < 16) {
                    int sA = (gbA * 4 + w) & (SLOTS - 1);
                    int sB = (gbB * 4 + w) & (SLOTS - 1);
                    int ch = ct * 16 + lane;
                    atomicAdd(&part[((L * SLOTS + sA) * 2 + 0) * 64 + ch], a);
                    atomicAdd(&part[((L * SLOTS + sA) * 2 + 1) * 64 + ch], b);
                    atomicAdd(&part[((L * SLOTS + sB) * 2 + 0) * 64 + ch], c);
                    atomicAdd(&part[((L * SLOTS + sB) * 2 + 1) * 64 + ch], d);
                }
            }
        };
        auto bnwb2 = [&](int L) {
#pragma unroll
            for (int ct = 0; ct < 4; ++ct) {
                int ch = ct * 16 + l15;
                float sc = bn[L * 128 + ch], sh = bn[L * 128 + 64 + ch];
#pragma unroll
                for (int rt = 0; rt < 2; ++rt)
#pragma unroll
                    for (int j = 0; j < 4; ++j) {
                        int gr = w * 32 + rt * 16 + g4 * 4 + j;
                        int off = gr * 128 + ((ch * 2) ^ ((gr & 7) << 4));
                        float vA = fmaxf(fmaf(accA[rt][ct][j], sc, sh), 0.f);
                        float vB = fmaxf(fmaf(accB[rt][ct][j], sc, sh), 0.f);
                        *(u16*)(AbA + off) = f2bf(vA);
                        *(u16*)(AbB + off) = f2bf(vB);
                        accA[rt][ct][j] = 0.f;
                        accB[rt][ct][j] = 0.f;
                    }
            }
        };

        // ---- layer 1 ----
        layer2(Wn);
        layerC2(Wc);

        if (PHASE == 1) {
            stats2(0);
            // shortcut MFMA for both groups (shared weight loads); rows 2-15 garbage
            f32x4 shA[4], shB[4];
#pragma unroll
            for (int ct = 0; ct < 4; ++ct) {
                shA[ct] = (f32x4){0.f, 0.f, 0.f, 0.f};
                shB[ct] = (f32x4){0.f, 0.f, 0.f, 0.f};
            }
#pragma unroll
            for (int ks = 0; ks < 2; ++ks) {
                int arow = (l15 < 2) ? (2 * w + l15) : (2 * w);
                bf8v aA = *(const bf8v*)(ceA + arow * 128 + ks * 64 + g4 * 16);
                bf8v aB = *(const bf8v*)(ceB + arow * 128 + ks * 64 + g4 * 16);
#pragma unroll
                for (int ct = 0; ct < 4; ++ct) {
                    bf8v b = *(const bf8v*)((const char*)scWb + (ct * 16 + l15) * 128 + ks * 64 + g4 * 16);
                    shA[ct] = MFMA16(aA, b, shA[ct]);
                    shB[ct] = MFMA16(aB, b, shB[ct]);
                }
            }
            // masked stats (valid rows: g4==0, j<2) -> L=3
#pragma unroll
            for (int ct = 0; ct < 4; ++ct) {
                float uA = (g4 == 0) ? shA[ct][0] : 0.f;
                float vA = (g4 == 0) ? shA[ct][1] : 0.f;
                float uB = (g4 == 0) ? shB[ct][0] : 0.f;
                float vB = (g4 == 0) ? shB[ct][1] : 0.f;
                float a = uA + vA, b = uA * uA + vA * vA;
                float c = uB + vB, d = uB * uB + vB * vB;
                a += __shfl_xor(a, 16); a += __shfl_xor(a, 32);
                b += __shfl_xor(b, 16); b += __shfl_xor(b, 32);
                c += __shfl_xor(c, 16); c += __shfl_xor(c, 32);
                d += __shfl_xor(d, 16); d += __shfl_xor(d, 32);
                if (lane < 16) {
                    int sA = (gbA * 4 + w) & (SLOTS - 1);
                    int sB = (gbB * 4 + w) & (SLOTS - 1);
                    int ch = ct * 16 + lane;
                    atomicAdd(&part[((3 * SLOTS + sA) * 2 + 0) * 64 + ch], a);
                    atomicAdd(&part[((3 * SLOTS + sA) * 2 + 1) * 64 + ch], b);
                    atomicAdd(&part[((3 * SLOTS + sB) * 2 + 0) * 64 + ch], c);
                    atomicAdd(&part[((3 * SLOTS + sB) * 2 + 1) * 64 + ch], d);
                }
            }
            continue;
        }

        bnwb2(0);
        layer2(W1b);
        if (PHASE == 2) { stats2(1); continue; }

        bnwb2(1);
        layer2(W2b);
        if (PHASE == 3) { stats2(2); continue; }

        // ---- PHASE 4: mean_k (consumes acc), shortcut, out — barrier-free ----
        {
            float m0A[4], m1A[4], m0B[4], m1B[4];
#pragma unroll
            for (int ct = 0; ct < 4; ++ct) {
                int ch = ct * 16 + l15;
                float sc = bn[2 * 128 + ch], sh = bn[2 * 128 + 64 + ch];
                float ma = 0.f, mb = 0.f, mc = 0.f, md = 0.f;
#pragma unroll
                for (int j = 0; j < 4; ++j) {
                    ma += fmaxf(fmaf(accA[0][ct][j], sc, sh), 0.f);
                    mb += fmaxf(fmaf(accA[1][ct][j], sc, sh), 0.f);
                    mc += fmaxf(fmaf(accB[0][ct][j], sc, sh), 0.f);
                    md += fmaxf(fmaf(accB[1][ct][j], sc, sh), 0.f);
                }
                ma += __shfl_xor(ma, 16); ma += __shfl_xor(ma, 32);
                mb += __shfl_xor(mb, 16); mb += __shfl_xor(mb, 32);
                mc += __shfl_xor(mc, 16); mc += __shfl_xor(mc, 32);
                md += __shfl_xor(md, 16); md += __shfl_xor(md, 32);
                m0A[ct] = ma; m1A[ct] = mb; m0B[ct] = mc; m1B[ct] = md;
            }
            // shortcut for both groups (shared weight loads)
            f32x4 shA[4], shB[4];
#pragma unroll
            for (int ct = 0; ct < 4; ++ct) {
                shA[ct] = (f32x4){0.f, 0.f, 0.f, 0.f};
                shB[ct] = (f32x4){0.f, 0.f, 0.f, 0.f};
            }
#pragma unroll
            for (int ks = 0; ks < 2; ++ks) {
                int arow = (l15 < 2) ? (2 * w + l15) : (2 * w);
                bf8v aA = *(const bf8v*)(ceA + arow * 128 + ks * 64 + g4 * 16);
                bf8v aB = *(const bf8v*)(ceB + arow * 128 + ks * 64 + g4 * 16);
#pragma unroll
                for (int ct = 0; ct < 4; ++ct) {
                    bf8v b = *(const bf8v*)((const char*)scWb + (ct * 16 + l15) * 128 + ks * 64 + g4 * 16);
                    shA[ct] = MFMA16(aA, b, shA[ct]);
                    shB[ct] = MFMA16(aB, b, shB[ct]);
                }
            }
            if (g4 == 0) {
#pragma unroll
                for (int ct = 0; ct < 4; ++ct) {
                    int ch = ct * 16 + l15;
                    float s3 = bn[3 * 128 + ch], h3 = bn[3 * 128 + 64 + ch];
                    scsA[2 * w + 0][ch] = fmaxf(fmaf(shA[ct][0], s3, h3), 0.f);
                    scsA[2 * w + 1][ch] = fmaxf(fmaf(shA[ct][1], s3, h3), 0.f);
                    scsB[2 * w + 0][ch] = fmaxf(fmaf(shB[ct][0], s3, h3), 0.f);
                    scsB[2 * w + 1][ch] = fmaxf(fmaf(shB[ct][1], s3, h3), 0.f);
                }
            }
            // wave-private scs rows: no barrier. Static-index selects only.
            int ph = g4 >> 1;             // 0: p=2w, 1: p=2w+1
            int p = 2 * w + ph;
            int cb2 = g4 & 1;
            int ch0 = (cb2 * 2) * 16 + l15;
            int ch1 = ch0 + 16;
            {
                float lo0 = cb2 ? m0A[2] : m0A[0], hi0 = cb2 ? m1A[2] : m1A[0];
                float lo1 = cb2 ? m0A[3] : m0A[1], hi1 = cb2 ? m1A[3] : m1A[1];
                float mva = ph ? hi0 : lo0;
                float mvb = ph ? hi1 : lo1;
                float* ob = out + (rbA + p) * CH;
                ob[ch0] = mva * 0.0625f + scsA[p][ch0];
                ob[ch1] = mvb * 0.0625f + scsA[p][ch1];
            }
            {
                float lo0 = cb2 ? m0B[2] : m0B[0], hi0 = cb2 ? m1B[2] : m1B[0];
                float lo1 = cb2 ? m0B[3] : m0B[1], hi1 = cb2 ? m1B[3] : m1B[1];
                float mva = ph ? hi0 : lo0;
                float mvb = ph ? hi1 : lo1;
                float* ob = out + (rbB + p) * CH;
                ob[ch0] = mva * 0.0625f + scsB[p][ch0];
                ob[ch1] = mvb * 0.0625f + scsB[p][ch1];
            }
        }
    }
}

extern "C" void kernel_launch(void* const* d_in, const int* in_sizes, int n_in,
                              void* d_out, int out_size, void* d_ws, size_t ws_size,
                              hipStream_t stream) {
    const float* points = (const float*)d_in[0];
    const float* feats  = (const float*)d_in[1];
    const float* W0  = (const float*)d_in[2];
    const float* g0  = (const float*)d_in[3];
    const float* b0  = (const float*)d_in[4];
    const float* W1  = (const float*)d_in[5];
    const float* g1  = (const float*)d_in[6];
    const float* b1  = (const float*)d_in[7];
    const float* W2  = (const float*)d_in[8];
    const float* g2  = (const float*)d_in[9];
    const float* b2  = (const float*)d_in[10];
    const float* scW = (const float*)d_in[11];
    const float* scg = (const float*)d_in[12];
    const float* scb = (const float*)d_in[13];
    float* out = (float*)d_out;

    char* ws = (char*)d_ws;
    int*   idx  = (int*)(ws + OFF_IDX);
    float* part = (float*)(ws + OFF_PART);
    float* bn   = (float*)(ws + OFF_BN);
    u16*   Wn   = (u16*)(ws + OFF_WN);
    u16*   Wc   = (u16*)(ws + OFF_WC);
    u16*   W1b  = (u16*)(ws + OFF_W1B);
    u16*   W2b  = (u16*)(ws + OFF_W2B);
    u16*   scWb = (u16*)(ws + OFF_SCWB);
    u16*   fb16 = (u16*)(ws + OFF_FB16);

    hipMemsetAsync(part, 0, PART_BYTES, stream);
    prep_weights<<<16, 256, 0, stream>>>(W0, W1, W2, scW, Wn, Wc, W1b, W2b, scWb);
    feats_to_bf16<<<2048, 256, 0, stream>>>(feats, fb16);
    knn_kernel<<<NB * 2, 256, 0, stream>>>(points, idx);

    mlp_phase<1><<<GRID_MLP, 256, 0, stream>>>(fb16, idx, Wn, Wc, W1b, W2b, scWb, bn, part, out);
    finalize_bn<<<2, 64, 0, stream>>>(part, bn, g0, b0, g1, b1, g2, b2, scg, scb, 0, 3);
    mlp_phase<2><<<GRID_MLP, 256, 0, stream>>>(fb16, idx, Wn, Wc, W1b, W2b, scWb, bn, part, out);
    finalize_bn<<<1, 64, 0, stream>>>(part, bn, g0, b0, g1, b1, g2, b2, scg, scb, 1, 1);
    mlp_phase<3><<<GRID_MLP, 256, 0, stream>>>(fb16, idx, Wn, Wc, W1b, W2b, scWb, bn, part, out);
    finalize_bn<<<1, 64, 0, stream>>>(part, bn, g0, b0, g1, b1, g2, b2, scg, scb, 2, 2);
    mlp_phase<4><<<GRID_MLP, 256, 0, stream>>>(fb16, idx, Wn, Wc, W1b, W2b, scWb, bn, part, out);
}